// Round 1
// baseline (938.984 us; speedup 1.0000x reference)
//
#include <hip/hip_runtime.h>
#include <hip/hip_bf16.h>

// Problem constants (reference: B,S,H,NH,HD = 2,2048,4096,32,128)
constexpr int Bc  = 2;
constexpr int Sc  = 2048;
constexpr int Hc  = 4096;
constexpr int NHc = 32;
constexpr int HDc = 128;

typedef __attribute__((ext_vector_type(8))) __bf16 bf16x8;
typedef __attribute__((ext_vector_type(4))) __bf16 bf16x4;
typedef __attribute__((ext_vector_type(4))) float  f32x4;

// ---------------------------------------------------------------------------
// fp32 -> bf16 conversion (vectorized, grid-stride free since sizes divide)
// ---------------------------------------------------------------------------
__global__ void cvt_f32_bf16(const float* __restrict__ in, __bf16* __restrict__ out, int n) {
    int i = (blockIdx.x * blockDim.x + threadIdx.x) * 4;
    if (i >= n) return;
    const float4 v = *(const float4*)(in + i);
    bf16x4 o;
    o[0] = (__bf16)v.x; o[1] = (__bf16)v.y; o[2] = (__bf16)v.z; o[3] = (__bf16)v.w;
    *(bf16x4*)(out + i) = o;
}

// Build fused KV weight: rows 0..127 = Wk, rows 128..255 = Wv  (256 x 4096)
__global__ void build_wkv(const float* __restrict__ Wk, const float* __restrict__ Wv,
                          __bf16* __restrict__ out) {
    int i = (blockIdx.x * blockDim.x + threadIdx.x) * 4;   // over 256*4096
    if (i >= 256 * Hc) return;
    int row = i >> 12;           // /4096
    int col = i & (Hc - 1);
    const float* src = (row < HDc) ? (Wk + (long)row * Hc + col)
                                   : (Wv + (long)(row - HDc) * Hc + col);
    const float4 v = *(const float4*)src;
    bf16x4 o;
    o[0] = (__bf16)v.x; o[1] = (__bf16)v.y; o[2] = (__bf16)v.z; o[3] = (__bf16)v.w;
    *(bf16x4*)(out + i) = o;
}

// ---------------------------------------------------------------------------
// NT GEMM:  C[m][n] = sum_k A[m][k] * B[n][k]   (A: MxK, B: NxK, row-major bf16)
// 128x128 block tile, BK=32, 256 threads (4 waves, 2x2 of 64x64), mfma 16x16x32.
// ---------------------------------------------------------------------------
template <typename OUT>
__global__ __launch_bounds__(256)
void gemm_bt(const __bf16* __restrict__ A, const __bf16* __restrict__ B,
             OUT* __restrict__ C, int M, int N, int K) {
    __shared__ __bf16 As[128][40];   // 32 k + 8 pad  (row stride 80B -> 2-way, free)
    __shared__ __bf16 Bs[128][40];

    const int tid  = threadIdx.x;
    const int m0   = blockIdx.y * 128;
    const int n0   = blockIdx.x * 128;
    const int wave = tid >> 6, lane = tid & 63;
    const int wr   = (wave >> 1) * 64;    // wave row offset in tile
    const int wc   = (wave & 1) * 64;     // wave col offset in tile
    const int lrow = lane & 15, quad = lane >> 4;

    f32x4 acc[4][4] = {};

    // staging loader: thread t loads 16B at (row = t/4 [+64], col = (t%4)*8)
    const int lr = tid >> 2;
    const int lc = (tid & 3) * 8;
    const __bf16* Ap = A + (long)(m0 + lr) * K + lc;
    const __bf16* Bp = B + (long)(n0 + lr) * K + lc;
    const long rowK64 = (long)64 * K;

    int4 a0 = *(const int4*)(Ap);
    int4 a1 = *(const int4*)(Ap + rowK64);
    int4 b0 = *(const int4*)(Bp);
    int4 b1 = *(const int4*)(Bp + rowK64);

    const int nk = K >> 5;
    for (int kt = 0; kt < nk; ++kt) {
        __syncthreads();
        *(int4*)&As[lr][lc]      = a0;
        *(int4*)&As[lr + 64][lc] = a1;
        *(int4*)&Bs[lr][lc]      = b0;
        *(int4*)&Bs[lr + 64][lc] = b1;
        if (kt + 1 < nk) {
            const long ko = (long)(kt + 1) * 32;
            a0 = *(const int4*)(Ap + ko);
            a1 = *(const int4*)(Ap + rowK64 + ko);
            b0 = *(const int4*)(Bp + ko);
            b1 = *(const int4*)(Bp + rowK64 + ko);
        }
        __syncthreads();

        bf16x8 af[4], bfv[4];
#pragma unroll
        for (int i = 0; i < 4; ++i) af[i]  = *(const bf16x8*)&As[wr + i * 16 + lrow][quad * 8];
#pragma unroll
        for (int j = 0; j < 4; ++j) bfv[j] = *(const bf16x8*)&Bs[wc + j * 16 + lrow][quad * 8];
#pragma unroll
        for (int i = 0; i < 4; ++i)
#pragma unroll
            for (int j = 0; j < 4; ++j)
                acc[i][j] = __builtin_amdgcn_mfma_f32_16x16x32_bf16(af[i], bfv[j], acc[i][j], 0, 0, 0);
    }

    // epilogue: C row = m0+wr+i*16+quad*4+r, col = n0+wc+j*16+lrow
#pragma unroll
    for (int i = 0; i < 4; ++i) {
        const int row = m0 + wr + i * 16 + quad * 4;
#pragma unroll
        for (int j = 0; j < 4; ++j) {
            const int col = n0 + wc + j * 16 + lrow;
            OUT* cp = C + (long)row * N + col;
#pragma unroll
            for (int r = 0; r < 4; ++r) cp[(long)r * N] = (OUT)acc[i][j][r];
        }
    }
}

// ---------------------------------------------------------------------------
// RoPE on Q (in-place, B*S x H, per-head HD=128), scale folded in.
// thread <-> (row, head, 8-wide d-block in lower half)
// ---------------------------------------------------------------------------
__global__ void rope_q(__bf16* __restrict__ Q, const float* __restrict__ cosb,
                       const float* __restrict__ sinb, float scale) {
    int gid  = blockIdx.x * blockDim.x + threadIdx.x;  // B*S*NH*8
    int row  = gid >> 8;                               // B*S
    int rem  = gid & 255;
    int h    = rem >> 3;
    int dblk = (rem & 7) * 8;
    int s    = row & (Sc - 1);
    __bf16* p = Q + (long)row * Hc + h * HDc;
    const float* cp = cosb + s * HDc;
    const float* sp = sinb + s * HDc;
    bf16x8 lo = *(bf16x8*)(p + dblk);
    bf16x8 hi = *(bf16x8*)(p + dblk + 64);
    bf16x8 olo, ohi;
#pragma unroll
    for (int j = 0; j < 8; ++j) {
        float ql = (float)lo[j], qh = (float)hi[j];
        float cl = cp[dblk + j],      sl = sp[dblk + j];
        float ch = cp[dblk + 64 + j], sh = sp[dblk + 64 + j];
        olo[j] = (__bf16)((ql * cl - qh * sl) * scale);
        ohi[j] = (__bf16)((qh * ch + ql * sh) * scale);
    }
    *(bf16x8*)(p + dblk)      = olo;
    *(bf16x8*)(p + dblk + 64) = ohi;
}

// RoPE on K (cols 0..127 of KV buffer, ld=256), no scale.
__global__ void rope_k(__bf16* __restrict__ KV, const float* __restrict__ cosb,
                       const float* __restrict__ sinb) {
    int gid  = blockIdx.x * blockDim.x + threadIdx.x;  // B*S*8
    int row  = gid >> 3;
    int dblk = (gid & 7) * 8;
    int s    = row & (Sc - 1);
    __bf16* p = KV + (long)row * 256;
    const float* cp = cosb + s * HDc;
    const float* sp = sinb + s * HDc;
    bf16x8 lo = *(bf16x8*)(p + dblk);
    bf16x8 hi = *(bf16x8*)(p + dblk + 64);
    bf16x8 olo, ohi;
#pragma unroll
    for (int j = 0; j < 8; ++j) {
        float ql = (float)lo[j], qh = (float)hi[j];
        float cl = cp[dblk + j],      sl = sp[dblk + j];
        float ch = cp[dblk + 64 + j], sh = sp[dblk + 64 + j];
        olo[j] = (__bf16)(ql * cl - qh * sl);
        ohi[j] = (__bf16)(qh * ch + ql * sh);
    }
    *(bf16x8*)(p + dblk)      = olo;
    *(bf16x8*)(p + dblk + 64) = ohi;
}

// V transpose: Vt[b][d][s] = KV[(b*S+s)*256 + 128 + d]
__global__ void vtrans(const __bf16* __restrict__ KV, __bf16* __restrict__ Vt) {
    int gid = blockIdx.x * blockDim.x + threadIdx.x;   // B*HD*S
    int b   = gid >> 18;                               // HD*S = 262144
    int r   = gid & (HDc * Sc - 1);
    int d   = r >> 11;
    int s   = r & (Sc - 1);
    Vt[gid] = KV[((long)(b * Sc + s)) * 256 + HDc + d];
}

// ---------------------------------------------------------------------------
// Causal MQA flash attention.
// grid: (S/64, B*NH). 256 threads = 4 waves; wave w owns Q rows qt*64+w*16..+16.
// KV tiles of 64. Q frags in registers; K tile + Vt tile in LDS; P via LDS.
// ---------------------------------------------------------------------------
__global__ __launch_bounds__(256)
void attn(const __bf16* __restrict__ Q,    // (B*S, H), rope'd & pre-scaled
          const __bf16* __restrict__ KV,   // (B*S, 256): cols 0..127 = K (rope'd)
          const __bf16* __restrict__ Vt,   // (B, HD, S)
          __bf16* __restrict__ O) {        // (B*S, H)
    const int qt   = blockIdx.x;
    const int bh   = blockIdx.y;
    const int b    = bh >> 5, h = bh & 31;
    const int tid  = threadIdx.x;
    const int wave = tid >> 6, lane = tid & 63;
    const int lrow = lane & 15, quad = lane >> 4;

    __shared__ __bf16 Ks[64][136];    // 64 kv x 128 d (+8 pad)
    __shared__ __bf16 Vs[128][72];    // 128 d x 64 kv (+8 pad)
    __shared__ __bf16 Ps[4][16][72];  // per-wave P tile 16 q x 64 kv (+8 pad)

    const int qrow_base = qt * 64 + wave * 16;

    bf16x8 aq[4];
    {
        const __bf16* qp = Q + (long)(b * Sc + qrow_base + lrow) * Hc + h * HDc + quad * 8;
#pragma unroll
        for (int c = 0; c < 4; ++c) aq[c] = *(const bf16x8*)(qp + c * 32);
    }

    f32x4 o[8] = {};
    float mstate[4], lstate[4];
#pragma unroll
    for (int r = 0; r < 4; ++r) { mstate[r] = -3.0e38f; lstate[r] = 0.f; }

    for (int kt = 0; kt <= qt; ++kt) {
        __syncthreads();
        // stage K tile (64x128) and Vt tile (128x64)
#pragma unroll
        for (int rr = 0; rr < 4; ++rr) {
            int e = rr * 2048 + tid * 8;
            int row = e >> 7, col = e & 127;
            *(int4*)&Ks[row][col] =
                *(const int4*)(KV + (long)(b * Sc + kt * 64 + row) * 256 + col);
        }
#pragma unroll
        for (int rr = 0; rr < 4; ++rr) {
            int e = rr * 2048 + tid * 8;
            int row = e >> 6, col = e & 63;
            *(int4*)&Vs[row][col] =
                *(const int4*)(Vt + (long)(b * HDc + row) * Sc + kt * 64 + col);
        }
        __syncthreads();

        // S = Q K^T  (16 q x 64 kv per wave)
        f32x4 sc[4];
#pragma unroll
        for (int ct = 0; ct < 4; ++ct) {
            f32x4 s = {};
#pragma unroll
            for (int c = 0; c < 4; ++c) {
                bf16x8 bk = *(const bf16x8*)&Ks[ct * 16 + lrow][c * 32 + quad * 8];
                s = __builtin_amdgcn_mfma_f32_16x16x32_bf16(aq[c], bk, s, 0, 0, 0);
            }
            sc[ct] = s;
        }

        if (kt == qt) {  // diagonal tile: causal mask
#pragma unroll
            for (int ct = 0; ct < 4; ++ct) {
                int kv = kt * 64 + ct * 16 + lrow;
#pragma unroll
                for (int r = 0; r < 4; ++r) {
                    int qr = qrow_base + quad * 4 + r;
                    if (kv > qr) sc[ct][r] = -3.0e38f;
                }
            }
        }

        // online softmax
        float mnew[4], alpha[4], rsum[4];
#pragma unroll
        for (int r = 0; r < 4; ++r) {
            float mx = fmaxf(fmaxf(sc[0][r], sc[1][r]), fmaxf(sc[2][r], sc[3][r]));
#pragma unroll
            for (int off = 1; off < 16; off <<= 1) mx = fmaxf(mx, __shfl_xor(mx, off, 64));
            mnew[r]  = fmaxf(mstate[r], mx);
            alpha[r] = __expf(mstate[r] - mnew[r]);
            mstate[r] = mnew[r];
            rsum[r] = 0.f;
        }
#pragma unroll
        for (int ct = 0; ct < 4; ++ct)
#pragma unroll
            for (int r = 0; r < 4; ++r) {
                float p = __expf(sc[ct][r] - mnew[r]);
                sc[ct][r] = p;
                rsum[r] += p;
            }
#pragma unroll
        for (int r = 0; r < 4; ++r) {
#pragma unroll
            for (int off = 1; off < 16; off <<= 1) rsum[r] += __shfl_xor(rsum[r], off, 64);
            lstate[r] = lstate[r] * alpha[r] + rsum[r];
        }
#pragma unroll
        for (int dt = 0; dt < 8; ++dt)
#pragma unroll
            for (int r = 0; r < 4; ++r) o[dt][r] *= alpha[r];

        // P -> LDS (C-layout -> A-layout round trip)
#pragma unroll
        for (int ct = 0; ct < 4; ++ct)
#pragma unroll
            for (int r = 0; r < 4; ++r)
                Ps[wave][quad * 4 + r][ct * 16 + lrow] = (__bf16)sc[ct][r];
        __syncthreads();

        // O += P V
#pragma unroll
        for (int ks = 0; ks < 2; ++ks) {
            bf16x8 ap = *(const bf16x8*)&Ps[wave][lrow][ks * 32 + quad * 8];
#pragma unroll
            for (int dt = 0; dt < 8; ++dt) {
                bf16x8 bv = *(const bf16x8*)&Vs[dt * 16 + lrow][ks * 32 + quad * 8];
                o[dt] = __builtin_amdgcn_mfma_f32_16x16x32_bf16(ap, bv, o[dt], 0, 0, 0);
            }
        }
    }

    // epilogue: O /= l, write (B*S, H)
#pragma unroll
    for (int r = 0; r < 4; ++r) {
        float inv = 1.f / lstate[r];
        int qr = qrow_base + quad * 4 + r;
        __bf16* op = O + (long)(b * Sc + qr) * Hc + h * HDc;
#pragma unroll
        for (int dt = 0; dt < 8; ++dt) op[dt * 16 + lrow] = (__bf16)(o[dt][r] * inv);
    }
}

// ---------------------------------------------------------------------------
extern "C" void kernel_launch(void* const* d_in, const int* in_sizes, int n_in,
                              void* d_out, int out_size, void* d_ws, size_t ws_size,
                              hipStream_t stream) {
    const float* hs   = (const float*)d_in[0];
    const float* cosb = (const float*)d_in[1];
    const float* sinb = (const float*)d_in[2];
    const float* Wq   = (const float*)d_in[3];
    const float* Wk   = (const float*)d_in[4];
    const float* Wv   = (const float*)d_in[5];
    const float* Wd   = (const float*)d_in[6];
    float* out = (float*)d_out;

    char* ws = (char*)d_ws;
    const long SZ_HS  = (long)Bc * Sc * Hc * 2;      // 32MB
    const long SZ_W   = (long)Hc * Hc * 2;           // 32MB
    const long SZ_KV  = (long)Bc * Sc * 256 * 2;     // 2MB
    const long SZ_VT  = (long)Bc * HDc * Sc * 2;     // 1MB
    __bf16* hs16  = (__bf16*)(ws);
    __bf16* wq16  = (__bf16*)(ws + SZ_HS);
    __bf16* wkv16 = (__bf16*)(ws + SZ_HS + SZ_W);
    __bf16* q16   = (__bf16*)(ws + SZ_HS + SZ_W + SZ_KV);
    __bf16* kv16  = (__bf16*)(ws + SZ_HS + SZ_W + SZ_KV + SZ_HS);
    __bf16* vt16  = (__bf16*)(ws + SZ_HS + SZ_W + SZ_KV + SZ_HS + SZ_KV);
    __bf16* att16 = hs16;   // reuse: hidden dead after Q/KV GEMMs
    __bf16* wd16  = wq16;   // reuse: Wq dead after Q GEMM

    const int nHS = Bc * Sc * Hc;   // 16M
    const int nW  = Hc * Hc;        // 16M

    cvt_f32_bf16<<<nHS / 1024, 256, 0, stream>>>(hs, hs16, nHS);
    cvt_f32_bf16<<<nW / 1024, 256, 0, stream>>>(Wq, wq16, nW);
    build_wkv<<<(256 * Hc) / 1024, 256, 0, stream>>>(Wk, Wv, wkv16);

    gemm_bt<__bf16><<<dim3(Hc / 128, (Bc * Sc) / 128), 256, 0, stream>>>(
        hs16, wq16, q16, Bc * Sc, Hc, Hc);
    gemm_bt<__bf16><<<dim3(256 / 128, (Bc * Sc) / 128), 256, 0, stream>>>(
        hs16, wkv16, kv16, Bc * Sc, 256, Hc);

    cvt_f32_bf16<<<nW / 1024, 256, 0, stream>>>(Wd, wd16, nW);  // after Q GEMM

    const float scale = 0.08838834764831845f;  // 1/sqrt(128)
    rope_q<<<(Bc * Sc * NHc * 8) / 256, 256, 0, stream>>>(q16, cosb, sinb, scale);
    rope_k<<<(Bc * Sc * 8) / 256, 256, 0, stream>>>(kv16, cosb, sinb);
    vtrans<<<(Bc * HDc * Sc) / 256, 256, 0, stream>>>(kv16, vt16);

    attn<<<dim3(Sc / 64, Bc * NHc), 256, 0, stream>>>(q16, kv16, vt16, att16);

    gemm_bt<float><<<dim3(Hc / 128, (Bc * Sc) / 128), 256, 0, stream>>>(
        att16, wd16, out, Bc * Sc, Hc, Hc);
}